// Round 4
// baseline (467.786 us; speedup 1.0000x reference)
//
#include <hip/hip_runtime.h>

// HealEncoding v4: barrier-free grid-stride streaming.
// One thread = (pixel, level); wave64 = 16 pixels x 4 levels (level = lane>>4).
// Table staged to LDS ONCE per block (single barrier), then each wave loops
// grid-stride over pixel-groups with all 18 global loads issued up front,
// pure LDS+VALU consume, and a 4-shuffle in-wave transpose so the store is a
// contiguous float2 per lane (512 B per wave) -- no LDS exchange, no barriers.
//
// params        [4, 792, 2]  f32   (25 KB -> LDS)
// pixel_latlon  [4, B, 2]    f32
// neigh_latlon  [4, 8B, 2]   f32   (element i = j*B + b)
// pixel_index   [4, B]       i32
// neigh_index   [4, 8, B]    i32   (-1 = missing -> contributes 0)
// out           [B, 8]       f32   out[b, 4*f + l] = res[l][b][f]

#define NLEV 4
#define MAXSZ 792
#define TABSZ (NLEV * MAXSZ * 2)   // 6336 floats = 25344 B

__global__ __launch_bounds__(256, 4) void heal_encoding_kernel(
    const float* __restrict__ params,
    const float* __restrict__ pixel_latlon,
    const float* __restrict__ neigh_latlon,
    const int*   __restrict__ pixel_index,
    const int*   __restrict__ neigh_index,
    float* __restrict__ out,
    int B)
{
    __shared__ float stab[TABSZ];
    {
        const float4* p4 = (const float4*)params;
        float4*       s4 = (float4*)stab;
        for (int i = threadIdx.x; i < TABSZ / 4; i += 256)
            s4[i] = p4[i];
    }
    __syncthreads();   // the ONLY barrier in the kernel
    const float2* sp2 = (const float2*)stab;

    const int lane = threadIdx.x & 63;
    const int l    = lane >> 4;          // level 0..3
    const int p    = lane & 15;          // pixel slot within the 16-px group
    const int lbase = l * MAXSZ;

    // epilogue (in-wave transpose) lane mapping: lane i stores output floats
    // [2i, 2i+1] of the wave's 512 B region = pixel (i>>2), cols 2*(i&3), +1.
    // col c -> feature c>>2, level c&3.
    const int  l0 = (2 * (lane & 3)) & 3;        // 0,2,0,2
    const bool f1 = (lane & 3) >= 2;             // feature select
    const int  sA = (lane >> 2) + 16 * l0;       // source lane for col c0
    const int  sB = sA + 16;                     // source lane for col c0+1

    const float2* pll2 = (const float2*)pixel_latlon;
    const float2* nll2 = (const float2*)neigh_latlon;

    const int wavesPerBlock = 256 / 64;
    const int w = blockIdx.x * wavesPerBlock + (threadIdx.x >> 6);
    const int totalWaves = gridDim.x * wavesPerBlock;
    const int nGroups = (B + 15) >> 4;

    for (int g = w; g < nGroups; g += totalWaves) {
        const int px  = g * 16 + p;
        const int pxc = min(px, B - 1);          // clamp: loads unconditional

        // ---- issue ALL 18 loads back-to-back, no consumers between ----
        int    pi  = pixel_index[l * B + pxc];
        float2 pll = pll2[l * B + pxc];
        int    ni[8];
        float2 nl[8];
        #pragma unroll
        for (int j = 0; j < 8; ++j) {
            const int off = (l * 8 + j) * B + pxc;
            ni[j] = neigh_index[off];
            nl[j] = nll2[off];
        }

        // ---- consume: pure LDS + VALU ----
        float a0 = 0.0f, a1 = 0.0f;
        #pragma unroll
        for (int j = 0; j < 8; ++j) {
            float dth = nl[j].x - pll.x;
            float dph = nl[j].y - pll.y;
            float d   = sqrtf(dth * dth + dph * dph);
            float wgt = (ni[j] >= 0) ? (1.0f / d) : 0.0f;   // mask -> exactly 0
            float2 r  = sp2[lbase + (ni[j] >= 0 ? ni[j] : 0)];
            a0 += wgt * r.x;
            a1 += wgt * r.y;
        }
        float2 m = sp2[lbase + (pi < 0 ? 768 : pi)];        // residual last
        a0 += m.x;
        a1 += m.y;

        // ---- in-wave transpose: 4 shuffles -> contiguous float2 store ----
        float r0 = __shfl(a0, sA, 64);
        float r1 = __shfl(a1, sA, 64);
        float r2 = __shfl(a0, sB, 64);
        float r3 = __shfl(a1, sB, 64);
        float lo = f1 ? r1 : r0;
        float hi = f1 ? r3 : r2;

        const size_t obase = (size_t)g * 128 + 2 * lane;
        if (g * 16 + 16 <= B) {
            *(float2*)(out + obase) = make_float2(lo, hi);
        } else {                                   // ragged tail group
            if (obase     < (size_t)B * 8) out[obase]     = lo;
            if (obase + 1 < (size_t)B * 8) out[obase + 1] = hi;
        }
    }
}

extern "C" void kernel_launch(void* const* d_in, const int* in_sizes, int n_in,
                              void* d_out, int out_size, void* d_ws, size_t ws_size,
                              hipStream_t stream) {
    const float* params       = (const float*)d_in[0];
    const float* pixel_latlon = (const float*)d_in[1];
    const float* neigh_latlon = (const float*)d_in[2];
    const int*   pixel_index  = (const int*)d_in[3];
    const int*   neigh_index  = (const int*)d_in[4];
    float* out = (float*)d_out;

    int B = in_sizes[3] / NLEV;               // pixel_index has 4*B elements
    int nGroups = (B + 15) / 16;
    int blocks = (nGroups + 3) / 4;           // 4 waves (groups) per block/iter
    if (blocks > 2048) blocks = 2048;         // ~8 blocks/CU, grid-stride
    if (blocks < 1) blocks = 1;
    heal_encoding_kernel<<<blocks, 256, 0, stream>>>(
        params, pixel_latlon, neigh_latlon, pixel_index, neigh_index, out, B);
}

// Round 5
// 467.456 us; speedup vs baseline: 1.0007x; 1.0007x over previous
//
#include <hip/hip_runtime.h>

// HealEncoding v5: v4 + pinned load batch + v_rsq_f32.
// R4 post-mortem: VGPR=40 proved the compiler sank the 18-load batch into the
// consume loop (2-3 loads in flight/wave -> 1.6 TB/s latency-bound).
// Fix: __builtin_amdgcn_sched_barrier(0) between the load batch and consume
// pins all 18 loads (6.9 KB/wave) in flight; v_rsq_f32 replaces sqrt+div to
// shrink the consume phase.
//
// params        [4, 792, 2]  f32   (25 KB -> LDS)
// pixel_latlon  [4, B, 2]    f32
// neigh_latlon  [4, 8B, 2]   f32   (element i = j*B + b)
// pixel_index   [4, B]       i32
// neigh_index   [4, 8, B]    i32   (-1 = missing -> contributes 0)
// out           [B, 8]       f32   out[b, 4*f + l] = res[l][b][f]

#define NLEV 4
#define MAXSZ 792
#define TABSZ (NLEV * MAXSZ * 2)   // 6336 floats = 25344 B

extern "C" __device__ float __builtin_amdgcn_rsqf(float);

__global__ __launch_bounds__(256, 4) void heal_encoding_kernel(
    const float* __restrict__ params,
    const float* __restrict__ pixel_latlon,
    const float* __restrict__ neigh_latlon,
    const int*   __restrict__ pixel_index,
    const int*   __restrict__ neigh_index,
    float* __restrict__ out,
    int B)
{
    __shared__ float stab[TABSZ];
    {
        const float4* p4 = (const float4*)params;
        float4*       s4 = (float4*)stab;
        for (int i = threadIdx.x; i < TABSZ / 4; i += 256)
            s4[i] = p4[i];
    }
    __syncthreads();   // the ONLY barrier in the kernel
    const float2* sp2 = (const float2*)stab;

    const int lane = threadIdx.x & 63;
    const int l    = lane >> 4;          // level 0..3
    const int p    = lane & 15;          // pixel slot within the 16-px group
    const int lbase = l * MAXSZ;

    // epilogue (in-wave transpose) lane mapping: lane i stores output floats
    // [2i, 2i+1] = pixel (i>>2), cols 2*(i&3), 2*(i&3)+1; col c -> feat c>>2, lvl c&3.
    const int  l0 = (2 * (lane & 3)) & 3;        // 0,2,0,2
    const bool f1 = (lane & 3) >= 2;             // feature select
    const int  sA = (lane >> 2) + 16 * l0;       // source lane for col c0
    const int  sB = sA + 16;                     // source lane for col c0+1

    const float2* pll2 = (const float2*)pixel_latlon;
    const float2* nll2 = (const float2*)neigh_latlon;

    const int wavesPerBlock = 256 / 64;
    const int w = blockIdx.x * wavesPerBlock + (threadIdx.x >> 6);
    const int totalWaves = gridDim.x * wavesPerBlock;
    const int nGroups = (B + 15) >> 4;

    for (int g = w; g < nGroups; g += totalWaves) {
        const int px  = g * 16 + p;
        const int pxc = min(px, B - 1);          // clamp: loads unconditional

        // ---- load batch: 18 VMEM issues, pinned ahead of all consumers ----
        int    pi  = pixel_index[l * B + pxc];
        float2 pll = pll2[l * B + pxc];
        int    ni[8];
        float2 nl[8];
        #pragma unroll
        for (int j = 0; j < 8; ++j) {
            const int off = (l * 8 + j) * B + pxc;
            ni[j] = neigh_index[off];
            nl[j] = nll2[off];
        }
        __builtin_amdgcn_sched_barrier(0);   // nothing crosses: keep all 18 in flight

        // ---- consume: pure LDS + VALU (rsq replaces sqrt+div) ----
        float a0 = 0.0f, a1 = 0.0f;
        #pragma unroll
        for (int j = 0; j < 8; ++j) {
            float dth = nl[j].x - pll.x;
            float dph = nl[j].y - pll.y;
            float s   = dth * dth + dph * dph;
            float wgt = (ni[j] >= 0) ? __builtin_amdgcn_rsqf(s) : 0.0f; // mask->0
            float2 r  = sp2[lbase + (ni[j] >= 0 ? ni[j] : 0)];
            a0 += wgt * r.x;
            a1 += wgt * r.y;
        }
        float2 m = sp2[lbase + (pi < 0 ? 768 : pi)];        // residual last
        a0 += m.x;
        a1 += m.y;

        // ---- in-wave transpose: 4 shuffles -> contiguous float2 store ----
        float r0 = __shfl(a0, sA, 64);
        float r1 = __shfl(a1, sA, 64);
        float r2 = __shfl(a0, sB, 64);
        float r3 = __shfl(a1, sB, 64);
        float lo = f1 ? r1 : r0;
        float hi = f1 ? r3 : r2;

        const size_t obase = (size_t)g * 128 + 2 * lane;
        if (g * 16 + 16 <= B) {
            *(float2*)(out + obase) = make_float2(lo, hi);
        } else {                                   // ragged tail group
            if (obase     < (size_t)B * 8) out[obase]     = lo;
            if (obase + 1 < (size_t)B * 8) out[obase + 1] = hi;
        }
    }
}

extern "C" void kernel_launch(void* const* d_in, const int* in_sizes, int n_in,
                              void* d_out, int out_size, void* d_ws, size_t ws_size,
                              hipStream_t stream) {
    const float* params       = (const float*)d_in[0];
    const float* pixel_latlon = (const float*)d_in[1];
    const float* neigh_latlon = (const float*)d_in[2];
    const int*   pixel_index  = (const int*)d_in[3];
    const int*   neigh_index  = (const int*)d_in[4];
    float* out = (float*)d_out;

    int B = in_sizes[3] / NLEV;               // pixel_index has 4*B elements
    int nGroups = (B + 15) / 16;
    int blocks = (nGroups + 3) / 4;           // 4 waves (groups) per block/iter
    if (blocks > 2048) blocks = 2048;         // grid-stride, ~8 blocks/CU queued
    if (blocks < 1) blocks = 1;
    heal_encoding_kernel<<<blocks, 256, 0, stream>>>(
        params, pixel_latlon, neigh_latlon, pixel_index, neigh_index, out, B);
}